// Round 3
// baseline (527.912 us; speedup 1.0000x reference)
//
#include <hip/hip_runtime.h>

// SMPL body model forward: fp32 pipeline.
// R2: LDS eliminated from hot loops.
//  - k_reg v3: v=lane (coalesced), k-rows via SGPR bases, register acc,
//    shuffle reduce, 2 v-splits + atomics.  (R1 was LDS-issue-bound: 4 SIMDs
//    share one LDS pipe; 9 b128/144 VALU-cyc = 3x oversubscribed.)
//  - k_posegemm v2: pose_feature precomputed to ws, read via s_load
//    (wave-uniform base), P columns coalesced vector loads, no LDS.

constexpr int N   = 512;
constexpr int V   = 6890;
constexpr int V3  = V * 3;        // 20670
constexpr int NJ  = 24;
constexpr int NB  = 10;
constexpr int NP  = 207;
constexpr int NK  = 95;           // 25 body + 70 face keypoints

// workspace layout (float offsets) — all offsets multiples of 4 floats (16B align)
constexpr size_t VP_OFF    = 0;                               // v_posed -> verts (in place), N*V3
constexpr size_t SCALE_OFF = (size_t)N * V3;                  // N
constexpr size_t SJ_OFF    = SCALE_OFF + N;                   // NB*72
constexpr size_t JT_OFF    = SJ_OFF + (size_t)NB * 72;        // 72
constexpr size_t J_OFF     = JT_OFF + 72;                     // N*72
constexpr size_t A_OFF     = J_OFF + (size_t)N * 72;          // N*288 (3x4 rows per joint)
constexpr size_t PF_OFF    = A_OFF + (size_t)N * 288;         // N*208 pose_feature (padded, pf[207]=0)

// ---------------------------------------------------------------------------
// SJ[k][j][c] = sum_v shapedirs[k, v*3+c] * Jreg[j,v];  Jt[j][c] = sum_v vt[v*3+c]*Jreg[j,v]
__global__ __launch_bounds__(256) void k_pre(const float* __restrict__ jreg,
                                             const float* __restrict__ sd,
                                             const float* __restrict__ vt,
                                             float* __restrict__ ws) {
    int jc = blockIdx.x;                 // 0..71
    int j = jc / 3, c = jc % 3;
    int tid = threadIdx.x;
    float acc[NB + 1];
#pragma unroll
    for (int t = 0; t <= NB; ++t) acc[t] = 0.f;
    for (int v = tid; v < V; v += 256) {
        float w = jreg[(size_t)j * V + v];
        int col = v * 3 + c;
#pragma unroll
        for (int k = 0; k < NB; ++k) acc[k] += w * sd[(size_t)k * V3 + col];
        acc[NB] += w * vt[col];
    }
    __shared__ float red[256];
    for (int t = 0; t <= NB; ++t) {
        red[tid] = acc[t];
        __syncthreads();
        for (int s = 128; s > 0; s >>= 1) {
            if (tid < s) red[tid] += red[tid + s];
            __syncthreads();
        }
        if (tid == 0) {
            if (t < NB) ws[SJ_OFF + (size_t)t * 72 + jc] = red[0];
            else        ws[JT_OFF + jc] = red[0];
        }
        __syncthreads();
    }
}

// ---------------------------------------------------------------------------
__global__ __launch_bounds__(256) void k_scale(const float* __restrict__ betas,
                                               const float* __restrict__ vt,
                                               const float* __restrict__ sd,
                                               float* __restrict__ ws) {
    int n = blockIdx.x * 256 + threadIdx.x;
    if (n >= N) return;
    const int idx[4] = {2802 * 3 + 1, 6262 * 3 + 1, 2237 * 3 + 1, 6728 * 3 + 1};
    float b[NB];
#pragma unroll
    for (int k = 0; k < NB; ++k) b[k] = betas[n * NB + k];
    float vals[4];
#pragma unroll
    for (int t = 0; t < 4; ++t) {
        float a = vt[idx[t]];
#pragma unroll
        for (int k = 0; k < NB; ++k) a += b[k] * sd[(size_t)k * V3 + idx[t]];
        vals[t] = a;
    }
    float h = vals[0] + vals[1] - vals[2] - vals[3];
    ws[SCALE_OFF + n] = 1.66f / h;
}

// ---------------------------------------------------------------------------
__global__ __launch_bounds__(256) void k_joints(const float* __restrict__ betas,
                                                float* __restrict__ ws) {
    int t = blockIdx.x * 256 + threadIdx.x;
    if (t >= N * 72) return;
    int n = t / 72, jc = t - n * 72;
    float a = ws[JT_OFF + jc];
#pragma unroll
    for (int k = 0; k < NB; ++k) a += betas[n * NB + k] * ws[SJ_OFF + (size_t)k * 72 + jc];
    ws[J_OFF + t] = ws[SCALE_OFF + n] * a;
}

// ---------------------------------------------------------------------------
// FK: one block (1 wave) per batch item.
__global__ __launch_bounds__(64) void k_fk(const float* __restrict__ pose,
                                           float* __restrict__ ws) {
    int n = blockIdx.x;
    int tid = threadIdx.x;
    __shared__ float G[NJ * 12];
    __shared__ float Jl[NJ * 3];
    for (int e = tid; e < 72; e += 64) Jl[e] = ws[J_OFF + (size_t)n * 72 + e];
    __syncthreads();
    const int par[NJ] = {0,0,0,0,1,2,3,4,5,6,7,8,9,9,9,12,13,14,16,17,18,19,20,21};
    if (tid < 12) {
        int r = tid >> 2, c = tid & 3;
        G[tid] = (c < 3) ? pose[(size_t)n * 216 + r * 3 + c] : Jl[r];
    }
    __syncthreads();
    for (int i = 1; i < NJ; ++i) {
        int p = par[i];
        if (tid < 12) {
            int r = tid >> 2, c = tid & 3;
            const float* gp = &G[p * 12 + r * 4];
            float v;
            if (c < 3) {
                const float* Ri = pose + (size_t)n * 216 + i * 9;
                v = gp[0] * Ri[0 * 3 + c] + gp[1] * Ri[1 * 3 + c] + gp[2] * Ri[2 * 3 + c];
            } else {
                float t0 = Jl[i * 3 + 0] - Jl[p * 3 + 0];
                float t1 = Jl[i * 3 + 1] - Jl[p * 3 + 1];
                float t2 = Jl[i * 3 + 2] - Jl[p * 3 + 2];
                v = gp[0] * t0 + gp[1] * t1 + gp[2] * t2 + gp[3];
            }
            G[i * 12 + tid] = v;
        }
        __syncthreads();
    }
    for (int idx = tid; idx < 288; idx += 64) {
        int j = idx / 12, rc = idx - j * 12;
        int r = rc >> 2, c = rc & 3;
        float v;
        if (c < 3) v = G[j * 12 + rc];
        else {
            const float* g = &G[j * 12 + r * 4];
            v = g[3] - (g[0] * Jl[j * 3 + 0] + g[1] * Jl[j * 3 + 1] + g[2] * Jl[j * 3 + 2]);
        }
        ws[A_OFF + (size_t)n * 288 + idx] = v;
    }
}

// ---------------------------------------------------------------------------
// pf[n][k] = pose[n,1+k/9] - I   (flattened, padded to 208 with pf[207]=0)
__global__ __launch_bounds__(256) void k_pf(const float* __restrict__ pose,
                                            float* __restrict__ ws) {
    int t = blockIdx.x * 256 + threadIdx.x;
    if (t >= N * 208) return;
    int n = t / 208, k = t - n * 208;
    float v = 0.f;
    if (k < NP) {
        v = pose[(size_t)n * 216 + 9 + k];
        int km = k % 9;
        if (km == 0 || km == 4 || km == 8) v -= 1.f;
    }
    ws[PF_OFF + t] = v;
}

// ---------------------------------------------------------------------------
// v_posed[n,i] = pf[n,:] @ P[:,i] + scale[n]*(betas[n,:]@sd[:,i] + vt[i])
// No LDS. pf/betas/scale via s_load (wave-uniform base). P columns coalesced.
// block: 256 thr = (cl 0..127) x (nh 0..1); thread: 1 col x 64 n. Grid (162, 4).
__global__ __launch_bounds__(256) void k_posegemm(const float* __restrict__ betas,
                                                  const float* __restrict__ vt,
                                                  const float* __restrict__ sd,
                                                  const float* __restrict__ pdirs,
                                                  float* __restrict__ ws) {
    int tid = threadIdx.x;
    int cl = tid & 127;
    int nh = __builtin_amdgcn_readfirstlane(tid >> 7);   // wave-uniform -> SGPR
    int colv = blockIdx.x * 128 + cl;
    int col = (colv < V3) ? colv : (V3 - 1);
    int nbase = blockIdx.y * 128 + nh * 64;

    float acc[64];
#pragma unroll
    for (int nn = 0; nn < 64; ++nn) acc[nn] = 0.f;

    const float* pfb = ws + PF_OFF + (size_t)nbase * 208;
    for (int k4 = 0; k4 < 52; ++k4) {
        float pk[4];
#pragma unroll
        for (int kk = 0; kk < 4; ++kk) {
            int k = k4 * 4 + kk;
            if (k > 206) k = 206;            // row clamp; pf[207]==0 kills it
            pk[kk] = pdirs[(size_t)k * V3 + col];
        }
#pragma unroll
        for (int nn = 0; nn < 64; ++nn) {
            float4 pf4 = *reinterpret_cast<const float4*>(pfb + (size_t)nn * 208 + k4 * 4);
            acc[nn] += pf4.x * pk[0] + pf4.y * pk[1] + pf4.z * pk[2] + pf4.w * pk[3];
        }
    }
    // epilogue: + scale*(betas@sd + vt)
    float sdq[NB];
#pragma unroll
    for (int k = 0; k < NB; ++k) sdq[k] = sd[(size_t)k * V3 + col];
    float vti = vt[col];
    bool valid = (colv < V3);
    for (int nn = 0; nn < 64; ++nn) {
        const float* bn = betas + (size_t)(nbase + nn) * NB;   // uniform -> s_load
        float sdot = vti;
#pragma unroll
        for (int k = 0; k < NB; ++k) sdot += bn[k] * sdq[k];
        float sc = ws[SCALE_OFF + nbase + nn];                  // uniform -> s_load
        if (valid)
            ws[VP_OFF + (size_t)(nbase + nn) * V3 + colv] = acc[nn] + sc * sdot;
    }
}

// ---------------------------------------------------------------------------
// LBS in place over v_posed. (unchanged this round)
__global__ __launch_bounds__(256) void k_lbs(const float* __restrict__ lbsw,
                                             const float* __restrict__ trans,
                                             float* __restrict__ ws) {
    __shared__ float wl[256 * 25];
    int tid = threadIdx.x;
    int n = blockIdx.y;
    int v0 = blockIdx.x * 256;
    for (int e = tid; e < 256 * 24; e += 256) {
        int g = v0 * 24 + e;
        float val = (g < V * 24) ? lbsw[g] : 0.f;
        int vv = e / 24, j = e - vv * 24;
        wl[vv * 25 + j] = val;
    }
    __syncthreads();
    int v = v0 + tid;
    if (v >= V) return;
    const float* An = ws + A_OFF + (size_t)n * 288;
    size_t vp_idx = VP_OFF + (size_t)n * V3 + (size_t)v * 3;
    float p0 = ws[vp_idx + 0], p1 = ws[vp_idx + 1], p2 = ws[vp_idx + 2];
    float T[12];
#pragma unroll
    for (int e = 0; e < 12; ++e) T[e] = 0.f;
    for (int j = 0; j < NJ; ++j) {
        float w = wl[tid * 25 + j];
#pragma unroll
        for (int e = 0; e < 12; ++e) T[e] += w * An[j * 12 + e];
    }
    float x = T[0] * p0 + T[1] * p1 + T[2]  * p2 + T[3]  + trans[n * 3 + 0];
    float y = T[4] * p0 + T[5] * p1 + T[6]  * p2 + T[7]  + trans[n * 3 + 1];
    float z = T[8] * p0 + T[9] * p1 + T[10] * p2 + T[11] + trans[n * 3 + 2];
    ws[vp_idx + 0] = x;
    ws[vp_idx + 1] = y;
    ws[vp_idx + 2] = z;
}

// ---------------------------------------------------------------------------
// R2 k_reg: out[n,k,c] = sum_v reg[k,v] * verts[n,v,c].  NO LDS in hot loop.
// block 256 = (vl 0..7) x (nl 0..7) x (wave 0..3).  Thread: 16 k x 3 c x 1 n,
// v stream = vsplit*3456 + it*32 + w*8 + vl  (108 iters).
// reg row bases block-uniform (SGPR); vp loads coalesced 8-lane runs.
// End: shuffle-reduce over 8 v-lanes, LDS combine over 4 waves, atomicAdd
// (contention only across the 2 v-splits).
__global__ __launch_bounds__(256) void k_reg(const float* __restrict__ b25,
                                             const float* __restrict__ face,
                                             const float* __restrict__ ws_c,
                                             float* __restrict__ out) {
    int tid = threadIdx.x;
    int vl = tid & 7;
    int nl = (tid >> 3) & 7;
    int w  = __builtin_amdgcn_readfirstlane(tid >> 6);   // wave-uniform
    int kbase = blockIdx.x * 16;
    int n = blockIdx.y * 8 + nl;
    int vsplit = blockIdx.z;

    const float* rows[16];
#pragma unroll
    for (int j = 0; j < 16; ++j) {
        int k = kbase + j;
        if (k > 94) k = 94;                 // pad row; never stored
        rows[j] = (k < 25) ? (b25 + (size_t)k * V) : (face + (size_t)(k - 25) * V);
    }

    float acc[16][3];
#pragma unroll
    for (int j = 0; j < 16; ++j)
#pragma unroll
        for (int c = 0; c < 3; ++c) acc[j][c] = 0.f;

    const float* vpn = ws_c + VP_OFF + (size_t)n * V3;
    int voff = w * 8 + vl;
    for (int it = 0; it < 108; ++it) {
        int v = vsplit * 3456 + it * 32 + voff;
        if (v < V) {
            float p0 = vpn[v * 3 + 0];
            float p1 = vpn[v * 3 + 1];
            float p2 = vpn[v * 3 + 2];
#pragma unroll
            for (int j = 0; j < 16; ++j) {
                float r = rows[j][v];
                acc[j][0] += r * p0;
                acc[j][1] += r * p1;
                acc[j][2] += r * p2;
            }
        }
    }
    // reduce over the 8 v-lanes (lane bits 0..2)
#pragma unroll
    for (int j = 0; j < 16; ++j)
#pragma unroll
        for (int c = 0; c < 3; ++c) {
            float a = acc[j][c];
            a += __shfl_xor(a, 1, 64);
            a += __shfl_xor(a, 2, 64);
            a += __shfl_xor(a, 4, 64);
            acc[j][c] = a;
        }
    __shared__ float sm[4 * 8 * 48];
    if (vl == 0) {
        int base = (w * 8 + nl) * 48;
#pragma unroll
        for (int j = 0; j < 16; ++j)
#pragma unroll
            for (int c = 0; c < 3; ++c) sm[base + j * 3 + c] = acc[j][c];
    }
    __syncthreads();
    for (int e = tid; e < 8 * 48; e += 256) {
        int nl2 = e / 48, r = e - nl2 * 48;
        float s = sm[nl2 * 48 + r] + sm[(8 + nl2) * 48 + r]
                + sm[(16 + nl2) * 48 + r] + sm[(24 + nl2) * 48 + r];
        int j = r / 3, c = r - j * 3;
        int k = kbase + j;
        if (k < NK)
            atomicAdd(&out[(size_t)(blockIdx.y * 8 + nl2) * (NK * 3) + k * 3 + c], s);
    }
}

// ---------------------------------------------------------------------------
extern "C" void kernel_launch(void* const* d_in, const int* in_sizes, int n_in,
                              void* d_out, int out_size, void* d_ws, size_t ws_size,
                              hipStream_t stream) {
    const float* pose  = (const float*)d_in[0];
    const float* betas = (const float*)d_in[1];
    const float* trans = (const float*)d_in[2];
    const float* vt    = (const float*)d_in[3];
    const float* sd    = (const float*)d_in[4];
    const float* jreg  = (const float*)d_in[5];
    const float* pdirs = (const float*)d_in[6];
    const float* lbsw  = (const float*)d_in[7];
    const float* b25   = (const float*)d_in[8];
    const float* face  = (const float*)d_in[9];
    float* ws  = (float*)d_ws;
    float* out = (float*)d_out;

    hipMemsetAsync(d_out, 0, (size_t)out_size * sizeof(float), stream);

    k_pre   <<<72, 256, 0, stream>>>(jreg, sd, vt, ws);
    k_scale <<<2, 256, 0, stream>>>(betas, vt, sd, ws);
    k_pf    <<<(N * 208 + 255) / 256, 256, 0, stream>>>(pose, ws);
    k_joints<<<(N * 72 + 255) / 256, 256, 0, stream>>>(betas, ws);
    k_fk    <<<N, 64, 0, stream>>>(pose, ws);
    k_posegemm<<<dim3(162, 4), 256, 0, stream>>>(betas, vt, sd, pdirs, ws);
    k_lbs   <<<dim3(27, N), 256, 0, stream>>>(lbsw, trans, ws);
    k_reg   <<<dim3(6, 64, 2), 256, 0, stream>>>(b25, face, ws, out);
}

// Round 4
// 334.584 us; speedup vs baseline: 1.5778x; 1.5778x over previous
//
#include <hip/hip_runtime.h>

// SMPL body model forward.
// R3: v_posed GEMM moved to bf16 MFMA (16x16x32), fp32 accumulate.
//  - k_pf2 builds A = [pose_feature | scale*betas] bf16 [512][224] (k-minor)
//  - k_bt  builds B = [posedirs ; shapedirs] bf16 [20672][224] (k-minor, LDS transpose)
//  - k_gemm: 4 waves x 4 col-tiles, 7 K-steps, epilogue adds scale*vt in fp32.
// R2 k_reg (no-LDS, shuffle-reduce) kept; k_lbs kept.

constexpr int N   = 512;
constexpr int V   = 6890;
constexpr int V3  = V * 3;        // 20670
constexpr int NJ  = 24;
constexpr int NB  = 10;
constexpr int NP  = 207;
constexpr int NK  = 95;
constexpr int KP  = 224;          // padded K (207 pose + 10 shape + 1 unused + pad)

// workspace layout (float offsets)
constexpr size_t VP_OFF    = 0;                               // N*V3 verts (in place)
constexpr size_t SCALE_OFF = (size_t)N * V3;                  // N
constexpr size_t SJ_OFF    = SCALE_OFF + N;                   // NB*72
constexpr size_t JT_OFF    = SJ_OFF + (size_t)NB * 72;        // 72
constexpr size_t J_OFF     = JT_OFF + 72;                     // N*72
constexpr size_t A_OFF     = J_OFF + (size_t)N * 72;          // N*288
constexpr size_t BF_OFF    = A_OFF + (size_t)N * 288;         // bf16 region start (16B aligned)
// bf16 region (ushort elements): apf [512*224], then bp [20672*224]
constexpr size_t APF_U     = 0;
constexpr size_t BP_U      = (size_t)N * KP;                  // 114688
constexpr int    BP_COLS   = 20672;                           // V3 padded to 64

typedef short s16x8 __attribute__((ext_vector_type(8)));
typedef float f32x4 __attribute__((ext_vector_type(4)));

__device__ inline unsigned short f2bf(float f) {
    unsigned u = __float_as_uint(f);
    u += 0x7fffu + ((u >> 16) & 1u);   // round-to-nearest-even
    return (unsigned short)(u >> 16);
}

// ---------------------------------------------------------------------------
// SJ[k][j][c] = sum_v shapedirs[k, v*3+c]*Jreg[j,v];  Jt[j][c] = sum_v vt*Jreg
__global__ __launch_bounds__(256) void k_pre(const float* __restrict__ jreg,
                                             const float* __restrict__ sd,
                                             const float* __restrict__ vt,
                                             float* __restrict__ ws) {
    int jc = blockIdx.x;
    int j = jc / 3, c = jc % 3;
    int tid = threadIdx.x;
    float acc[NB + 1];
#pragma unroll
    for (int t = 0; t <= NB; ++t) acc[t] = 0.f;
    for (int v = tid; v < V; v += 256) {
        float w = jreg[(size_t)j * V + v];
        int col = v * 3 + c;
#pragma unroll
        for (int k = 0; k < NB; ++k) acc[k] += w * sd[(size_t)k * V3 + col];
        acc[NB] += w * vt[col];
    }
    __shared__ float red[256];
    for (int t = 0; t <= NB; ++t) {
        red[tid] = acc[t];
        __syncthreads();
        for (int s = 128; s > 0; s >>= 1) {
            if (tid < s) red[tid] += red[tid + s];
            __syncthreads();
        }
        if (tid == 0) {
            if (t < NB) ws[SJ_OFF + (size_t)t * 72 + jc] = red[0];
            else        ws[JT_OFF + jc] = red[0];
        }
        __syncthreads();
    }
}

// ---------------------------------------------------------------------------
__global__ __launch_bounds__(256) void k_scale(const float* __restrict__ betas,
                                               const float* __restrict__ vt,
                                               const float* __restrict__ sd,
                                               float* __restrict__ ws) {
    int n = blockIdx.x * 256 + threadIdx.x;
    if (n >= N) return;
    const int idx[4] = {2802 * 3 + 1, 6262 * 3 + 1, 2237 * 3 + 1, 6728 * 3 + 1};
    float b[NB];
#pragma unroll
    for (int k = 0; k < NB; ++k) b[k] = betas[n * NB + k];
    float vals[4];
#pragma unroll
    for (int t = 0; t < 4; ++t) {
        float a = vt[idx[t]];
#pragma unroll
        for (int k = 0; k < NB; ++k) a += b[k] * sd[(size_t)k * V3 + idx[t]];
        vals[t] = a;
    }
    float h = vals[0] + vals[1] - vals[2] - vals[3];
    ws[SCALE_OFF + n] = 1.66f / h;
}

// ---------------------------------------------------------------------------
__global__ __launch_bounds__(256) void k_joints(const float* __restrict__ betas,
                                                float* __restrict__ ws) {
    int t = blockIdx.x * 256 + threadIdx.x;
    if (t >= N * 72) return;
    int n = t / 72, jc = t - n * 72;
    float a = ws[JT_OFF + jc];
#pragma unroll
    for (int k = 0; k < NB; ++k) a += betas[n * NB + k] * ws[SJ_OFF + (size_t)k * 72 + jc];
    ws[J_OFF + t] = ws[SCALE_OFF + n] * a;
}

// ---------------------------------------------------------------------------
// FK: one block (1 wave) per batch item.
__global__ __launch_bounds__(64) void k_fk(const float* __restrict__ pose,
                                           float* __restrict__ ws) {
    int n = blockIdx.x;
    int tid = threadIdx.x;
    __shared__ float G[NJ * 12];
    __shared__ float Jl[NJ * 3];
    for (int e = tid; e < 72; e += 64) Jl[e] = ws[J_OFF + (size_t)n * 72 + e];
    __syncthreads();
    const int par[NJ] = {0,0,0,0,1,2,3,4,5,6,7,8,9,9,9,12,13,14,16,17,18,19,20,21};
    if (tid < 12) {
        int r = tid >> 2, c = tid & 3;
        G[tid] = (c < 3) ? pose[(size_t)n * 216 + r * 3 + c] : Jl[r];
    }
    __syncthreads();
    for (int i = 1; i < NJ; ++i) {
        int p = par[i];
        if (tid < 12) {
            int r = tid >> 2, c = tid & 3;
            const float* gp = &G[p * 12 + r * 4];
            float v;
            if (c < 3) {
                const float* Ri = pose + (size_t)n * 216 + i * 9;
                v = gp[0] * Ri[0 * 3 + c] + gp[1] * Ri[1 * 3 + c] + gp[2] * Ri[2 * 3 + c];
            } else {
                float t0 = Jl[i * 3 + 0] - Jl[p * 3 + 0];
                float t1 = Jl[i * 3 + 1] - Jl[p * 3 + 1];
                float t2 = Jl[i * 3 + 2] - Jl[p * 3 + 2];
                v = gp[0] * t0 + gp[1] * t1 + gp[2] * t2 + gp[3];
            }
            G[i * 12 + tid] = v;
        }
        __syncthreads();
    }
    for (int idx = tid; idx < 288; idx += 64) {
        int j = idx / 12, rc = idx - j * 12;
        int r = rc >> 2, c = rc & 3;
        float v;
        if (c < 3) v = G[j * 12 + rc];
        else {
            const float* g = &G[j * 12 + r * 4];
            v = g[3] - (g[0] * Jl[j * 3 + 0] + g[1] * Jl[j * 3 + 1] + g[2] * Jl[j * 3 + 2]);
        }
        ws[A_OFF + (size_t)n * 288 + idx] = v;
    }
}

// ---------------------------------------------------------------------------
// A build: apf[n][k] bf16. k<207: pose_feature; 207..216: scale*betas; else 0.
__global__ __launch_bounds__(256) void k_pf2(const float* __restrict__ pose,
                                             const float* __restrict__ betas,
                                             const float* __restrict__ ws,
                                             unsigned short* __restrict__ apf) {
    int n = blockIdx.x;
    int k = threadIdx.x;
    if (k >= KP) return;
    float v = 0.f;
    if (k < NP) {
        v = pose[(size_t)n * 216 + 9 + k];
        int km = k % 9;
        if (km == 0 || km == 4 || km == 8) v -= 1.f;
    } else if (k < NP + NB) {
        v = ws[SCALE_OFF + n] * betas[n * NB + (k - NP)];
    }
    apf[(size_t)n * KP + k] = f2bf(v);
}

// ---------------------------------------------------------------------------
// B build + transpose: bp[col][k] bf16, k-minor. rows 0..206 = pdirs,
// 207..216 = sd, rest 0; cols >= V3 zero. One block per 64 cols.
__global__ __launch_bounds__(256) void k_bt(const float* __restrict__ pdirs,
                                            const float* __restrict__ sd,
                                            unsigned short* __restrict__ bp) {
    __shared__ unsigned short t[KP * 64];
    int tid = threadIdx.x;
    int c0 = blockIdx.x * 64;
#pragma unroll 4
    for (int i = 0; i < 56; ++i) {
        int e = tid + 256 * i;
        int k = e >> 6, cl = e & 63;
        int col = c0 + cl;
        float v = 0.f;
        if (col < V3) {
            if (k < NP) v = pdirs[(size_t)k * V3 + col];
            else if (k < NP + NB) v = sd[(size_t)(k - NP) * V3 + col];
        }
        t[k * 64 + cl] = f2bf(v);
    }
    __syncthreads();
    for (int i = 0; i < 7; ++i) {
        int e = tid + 256 * i;
        int cl = e & 63, kc = e >> 6;    // kc 0..27
        s16x8 r;
#pragma unroll
        for (int j = 0; j < 8; ++j) r[j] = (short)t[(kc * 8 + j) * 64 + cl];
        *reinterpret_cast<s16x8*>(&bp[(size_t)(c0 + cl) * KP + kc * 8]) = r;
    }
}

// ---------------------------------------------------------------------------
// MFMA GEMM: vp[n][col] = A[n][:224] . B[:224][col] + scale[n]*vt[col]
// block 256 = 4 waves; wave -> 16 n-rows x 64 cols (4 x 16-col tiles).
// Fragment layouts (HW-verified, cdna_hip §3): A[m=lane&15][k=q*8+j],
// B[k=q*8+j][nn=lane&15], C/D col=lane&15, row=q*4+reg.
__global__ __launch_bounds__(256) void k_gemm(const unsigned short* __restrict__ apf,
                                              const unsigned short* __restrict__ bp,
                                              const float* __restrict__ vt,
                                              const float* __restrict__ ws,
                                              float* __restrict__ vp) {
    int tid = threadIdx.x;
    int lane = tid & 63;
    int w = tid >> 6;
    int m = lane & 15, q = lane >> 4;
    int n0 = blockIdx.y * 64 + w * 16;
    int c0 = blockIdx.x * 64;

    const unsigned short* arow = apf + (size_t)(n0 + m) * KP + q * 8;
    const unsigned short* b0 = bp + (size_t)(c0 + m) * KP + q * 8;
    const unsigned short* b1 = b0 + 16 * KP;
    const unsigned short* b2 = b0 + 32 * KP;
    const unsigned short* b3 = b0 + 48 * KP;

    f32x4 acc0 = {0.f, 0.f, 0.f, 0.f};
    f32x4 acc1 = acc0, acc2 = acc0, acc3 = acc0;
#pragma unroll
    for (int kk = 0; kk < 7; ++kk) {
        s16x8 a = *reinterpret_cast<const s16x8*>(arow + kk * 32);
        acc0 = __builtin_amdgcn_mfma_f32_16x16x32_bf16(
            a, *reinterpret_cast<const s16x8*>(b0 + kk * 32), acc0, 0, 0, 0);
        acc1 = __builtin_amdgcn_mfma_f32_16x16x32_bf16(
            a, *reinterpret_cast<const s16x8*>(b1 + kk * 32), acc1, 0, 0, 0);
        acc2 = __builtin_amdgcn_mfma_f32_16x16x32_bf16(
            a, *reinterpret_cast<const s16x8*>(b2 + kk * 32), acc2, 0, 0, 0);
        acc3 = __builtin_amdgcn_mfma_f32_16x16x32_bf16(
            a, *reinterpret_cast<const s16x8*>(b3 + kk * 32), acc3, 0, 0, 0);
    }
    float sc[4];
#pragma unroll
    for (int r = 0; r < 4; ++r) sc[r] = ws[SCALE_OFF + n0 + q * 4 + r];

    f32x4 accs[4] = {acc0, acc1, acc2, acc3};
#pragma unroll
    for (int ct = 0; ct < 4; ++ct) {
        int col = c0 + ct * 16 + m;
        if (col < V3) {
            float vtc = vt[col];
#pragma unroll
            for (int r = 0; r < 4; ++r) {
                int n = n0 + q * 4 + r;
                vp[(size_t)n * V3 + col] = accs[ct][r] + sc[r] * vtc;
            }
        }
    }
}

// ---------------------------------------------------------------------------
// LBS in place over v_posed.
__global__ __launch_bounds__(256) void k_lbs(const float* __restrict__ lbsw,
                                             const float* __restrict__ trans,
                                             float* __restrict__ ws) {
    __shared__ float wl[256 * 25];
    int tid = threadIdx.x;
    int n = blockIdx.y;
    int v0 = blockIdx.x * 256;
    for (int e = tid; e < 256 * 24; e += 256) {
        int g = v0 * 24 + e;
        float val = (g < V * 24) ? lbsw[g] : 0.f;
        int vv = e / 24, j = e - vv * 24;
        wl[vv * 25 + j] = val;
    }
    __syncthreads();
    int v = v0 + tid;
    if (v >= V) return;
    const float* An = ws + A_OFF + (size_t)n * 288;
    size_t vp_idx = VP_OFF + (size_t)n * V3 + (size_t)v * 3;
    float p0 = ws[vp_idx + 0], p1 = ws[vp_idx + 1], p2 = ws[vp_idx + 2];
    float T[12];
#pragma unroll
    for (int e = 0; e < 12; ++e) T[e] = 0.f;
    for (int j = 0; j < NJ; ++j) {
        float w = wl[tid * 25 + j];
#pragma unroll
        for (int e = 0; e < 12; ++e) T[e] += w * An[j * 12 + e];
    }
    float x = T[0] * p0 + T[1] * p1 + T[2]  * p2 + T[3]  + trans[n * 3 + 0];
    float y = T[4] * p0 + T[5] * p1 + T[6]  * p2 + T[7]  + trans[n * 3 + 1];
    float z = T[8] * p0 + T[9] * p1 + T[10] * p2 + T[11] + trans[n * 3 + 2];
    ws[vp_idx + 0] = x;
    ws[vp_idx + 1] = y;
    ws[vp_idx + 2] = z;
}

// ---------------------------------------------------------------------------
// k_reg (R2): out[n,k,c] = sum_v reg[k,v]*verts[n,v,c]. No LDS in hot loop.
__global__ __launch_bounds__(256) void k_reg(const float* __restrict__ b25,
                                             const float* __restrict__ face,
                                             const float* __restrict__ ws_c,
                                             float* __restrict__ out) {
    int tid = threadIdx.x;
    int vl = tid & 7;
    int nl = (tid >> 3) & 7;
    int w  = __builtin_amdgcn_readfirstlane(tid >> 6);
    int kbase = blockIdx.x * 16;
    int n = blockIdx.y * 8 + nl;
    int vsplit = blockIdx.z;

    const float* rows[16];
#pragma unroll
    for (int j = 0; j < 16; ++j) {
        int k = kbase + j;
        if (k > 94) k = 94;
        rows[j] = (k < 25) ? (b25 + (size_t)k * V) : (face + (size_t)(k - 25) * V);
    }
    float acc[16][3];
#pragma unroll
    for (int j = 0; j < 16; ++j)
#pragma unroll
        for (int c = 0; c < 3; ++c) acc[j][c] = 0.f;

    const float* vpn = ws_c + VP_OFF + (size_t)n * V3;
    int voff = w * 8 + vl;
    for (int it = 0; it < 108; ++it) {
        int v = vsplit * 3456 + it * 32 + voff;
        if (v < V) {
            float p0 = vpn[v * 3 + 0];
            float p1 = vpn[v * 3 + 1];
            float p2 = vpn[v * 3 + 2];
#pragma unroll
            for (int j = 0; j < 16; ++j) {
                float r = rows[j][v];
                acc[j][0] += r * p0;
                acc[j][1] += r * p1;
                acc[j][2] += r * p2;
            }
        }
    }
#pragma unroll
    for (int j = 0; j < 16; ++j)
#pragma unroll
        for (int c = 0; c < 3; ++c) {
            float a = acc[j][c];
            a += __shfl_xor(a, 1, 64);
            a += __shfl_xor(a, 2, 64);
            a += __shfl_xor(a, 4, 64);
            acc[j][c] = a;
        }
    __shared__ float sm[4 * 8 * 48];
    if (vl == 0) {
        int base = (w * 8 + nl) * 48;
#pragma unroll
        for (int j = 0; j < 16; ++j)
#pragma unroll
            for (int c = 0; c < 3; ++c) sm[base + j * 3 + c] = acc[j][c];
    }
    __syncthreads();
    for (int e = tid; e < 8 * 48; e += 256) {
        int nl2 = e / 48, r = e - nl2 * 48;
        float s = sm[nl2 * 48 + r] + sm[(8 + nl2) * 48 + r]
                + sm[(16 + nl2) * 48 + r] + sm[(24 + nl2) * 48 + r];
        int j = r / 3, c = r - j * 3;
        int k = kbase + j;
        if (k < NK)
            atomicAdd(&out[(size_t)(blockIdx.y * 8 + nl2) * (NK * 3) + k * 3 + c], s);
    }
}

// ---------------------------------------------------------------------------
extern "C" void kernel_launch(void* const* d_in, const int* in_sizes, int n_in,
                              void* d_out, int out_size, void* d_ws, size_t ws_size,
                              hipStream_t stream) {
    const float* pose  = (const float*)d_in[0];
    const float* betas = (const float*)d_in[1];
    const float* trans = (const float*)d_in[2];
    const float* vt    = (const float*)d_in[3];
    const float* sd    = (const float*)d_in[4];
    const float* jreg  = (const float*)d_in[5];
    const float* pdirs = (const float*)d_in[6];
    const float* lbsw  = (const float*)d_in[7];
    const float* b25   = (const float*)d_in[8];
    const float* face  = (const float*)d_in[9];
    float* ws  = (float*)d_ws;
    float* out = (float*)d_out;
    unsigned short* bf  = (unsigned short*)(ws + BF_OFF);
    unsigned short* apf = bf + APF_U;
    unsigned short* bp  = bf + BP_U;

    hipMemsetAsync(d_out, 0, (size_t)out_size * sizeof(float), stream);

    k_pre   <<<72, 256, 0, stream>>>(jreg, sd, vt, ws);
    k_scale <<<2, 256, 0, stream>>>(betas, vt, sd, ws);
    k_joints<<<(N * 72 + 255) / 256, 256, 0, stream>>>(betas, ws);
    k_fk    <<<N, 64, 0, stream>>>(pose, ws);
    k_bt    <<<BP_COLS / 64, 256, 0, stream>>>(pdirs, sd, bp);
    k_pf2   <<<N, 256, 0, stream>>>(pose, betas, ws, apf);
    k_gemm  <<<dim3(BP_COLS / 64, N / 64), 256, 0, stream>>>(apf, bp, vt, ws, ws + VP_OFF);
    k_lbs   <<<dim3(27, N), 256, 0, stream>>>(lbsw, trans, ws);
    k_reg   <<<dim3(6, 64, 2), 256, 0, stream>>>(b25, face, ws, out);
}